// Round 1
// baseline (939.634 us; speedup 1.0000x reference)
//
#include <hip/hip_runtime.h>
#include <cstdint>
#include <cstddef>

// ---------------------------------------------------------------------------
// Llama3 MHA (B=2,T=2048,E=4096,H=32,HKV=8,DH=128), bf16 MFMA pipeline:
//   cast -> fused QKV NT-GEMM -> rope(q,k)+v-transpose -> flash attn -> O GEMM
// ---------------------------------------------------------------------------

typedef __bf16 bf16_t;
typedef float  f32x4  __attribute__((ext_vector_type(4)));
typedef __bf16 bf16x8 __attribute__((ext_vector_type(8)));
typedef __bf16 bf16x4 __attribute__((ext_vector_type(4)));

static constexpr int kB   = 2;
static constexpr int kT   = 2048;
static constexpr int kE   = 4096;
static constexpr int kH   = 32;
static constexpr int kHKV = 8;
static constexpr int kDH  = 128;
static constexpr int kNQKV = kE + 2 * kHKV * kDH;   // 6144
static constexpr int kM    = kB * kT;               // 4096 rows

// async global->LDS, 16B per lane. LDS dest is wave-uniform base + lane*16.
__device__ __forceinline__ void gll16(const void* g, void* l) {
  __builtin_amdgcn_global_load_lds(
      (__attribute__((address_space(1))) void*)g,
      (__attribute__((address_space(3))) void*)l, 16, 0, 0);
}

// ---------------- fp32 -> bf16 cast (float4 vectorized) --------------------
__global__ void cast_f32_bf16_k(const float* __restrict__ in,
                                bf16_t* __restrict__ out, int n4) {
  int i = blockIdx.x * 256 + threadIdx.x;
  if (i >= n4) return;
  float4 v = reinterpret_cast<const float4*>(in)[i];
  bf16x4 o;
  o[0] = (__bf16)v.x; o[1] = (__bf16)v.y; o[2] = (__bf16)v.z; o[3] = (__bf16)v.w;
  reinterpret_cast<bf16x4*>(out)[i] = o;
}

// ---------------- rope cos/sin table (llama3 scaling, faithful port) -------
__global__ void rope_table_k(float* __restrict__ cosT, float* __restrict__ sinT) {
  int idx = blockIdx.x * 256 + threadIdx.x;            // T*64
  if (idx >= kT * 64) return;
  int t = idx >> 6, i = idx & 63;
  float ex  = (float)i / 64.0f;                         // arange(0,DH,2)/DH
  float inv = powf(500000.0f, -ex);
  float wl  = 6.283185307179586f / inv;
  const float cut_lo = 8192.0f / 4.0f;                  // 2048
  const float cut_hi = 8192.0f / 1.0f;                  // 8192
  float inv2 = (wl > cut_hi) ? inv * (1.0f / 32.0f) : inv;
  float smooth   = (8192.0f / wl - 1.0f) * (1.0f / 3.0f);
  float smoothed = (1.0f - smooth) * inv2 * (1.0f / 32.0f) + smooth * inv2;
  bool  medium   = (!(wl < cut_hi)) && (!(wl > cut_lo));  // always false (faithful)
  float invf = medium ? smoothed : inv2;
  float f = (float)t * invf;
  cosT[idx] = cosf(f);
  sinT[idx] = sinf(f);
}

// ---------------- rope on Q (+1/sqrt(DH) fold) , [B,T,H,DH]->[B,H,T,DH] ----
__global__ void rope_q_k(const bf16_t* __restrict__ QKV,
                         const float* __restrict__ cosT,
                         const float* __restrict__ sinT,
                         bf16_t* __restrict__ Qr) {
  int idx = blockIdx.x * 256 + threadIdx.x;            // B*T*H*64 = 2^23
  if (idx >= kB * kT * kH * 64) return;
  int i = idx & 63;
  int h = (idx >> 6) & 31;
  int t = (idx >> 11) & 2047;
  int b = idx >> 22;
  const bf16_t* src = QKV + (size_t)(b * kT + t) * kNQKV + h * kDH + i;
  float q1 = (float)src[0], q2 = (float)src[64];
  float c = cosT[(t << 6) + i], s = sinT[(t << 6) + i];
  const float sc = 0.08838834764831845f;               // 1/sqrt(128)
  bf16_t* dst = Qr + ((size_t)(b * kH + h) * kT + t) * kDH + i;
  dst[0]  = (__bf16)((q1 * c - q2 * s) * sc);
  dst[64] = (__bf16)((q2 * c + q1 * s) * sc);
}

// ---------------- rope on K, [B,T,HKV,DH]->[B,HKV,T,DH] --------------------
__global__ void rope_k_k(const bf16_t* __restrict__ QKV,
                         const float* __restrict__ cosT,
                         const float* __restrict__ sinT,
                         bf16_t* __restrict__ Kr) {
  int idx = blockIdx.x * 256 + threadIdx.x;            // B*T*HKV*64 = 2^21
  if (idx >= kB * kT * kHKV * 64) return;
  int i = idx & 63;
  int h = (idx >> 6) & 7;
  int t = (idx >> 9) & 2047;
  int b = idx >> 20;
  const bf16_t* src = QKV + (size_t)(b * kT + t) * kNQKV + kE + h * kDH + i;
  float k1 = (float)src[0], k2 = (float)src[64];
  float c = cosT[(t << 6) + i], s = sinT[(t << 6) + i];
  bf16_t* dst = Kr + ((size_t)(b * kHKV + h) * kT + t) * kDH + i;
  dst[0]  = (__bf16)(k1 * c - k2 * s);
  dst[64] = (__bf16)(k2 * c + k1 * s);
}

// ---------------- V transpose: [B,T,HKV,DH] -> Vt [B,HKV,DH,T] -------------
__global__ void vtrans_k(const bf16_t* __restrict__ QKV, bf16_t* __restrict__ Vt) {
  __shared__ bf16_t tile[64 * 130];                    // pad 130: conflict-free
  int bidx = blockIdx.x;                               // B*HKV*(T/64) = 512
  int tt = bidx & 31;
  int h  = (bidx >> 5) & 7;
  int b  = bidx >> 8;
  int tid = threadIdx.x;
  int t0 = tt * 64;
  for (int it = 0; it < 32; ++it) {
    int e = it * 256 + tid;
    int tr = e >> 7, d = e & 127;
    tile[tr * 130 + d] =
        QKV[(size_t)(b * kT + t0 + tr) * kNQKV + kE + kHKV * kDH + h * kDH + d];
  }
  __syncthreads();
  for (int j = 0; j < 32; ++j) {
    int o = j * 256 + tid;
    int d = o >> 6, tr = o & 63;
    Vt[((size_t)(b * kHKV + h) * kDH + d) * kT + t0 + tr] = tile[tr * 130 + d];
  }
}

// ---------------- NT GEMM: C[M,N] = A[M,K] * B[N,K]^T  (bf16, fp32 acc) ----
// m97 structure: 128x128 tile, BK=32, 4 waves, global_load_lds(16B), 2 barriers.
template <bool OUT_BF16>
__global__ __launch_bounds__(256, 2)
void gemm_nt_k(const bf16_t* __restrict__ A, const bf16_t* __restrict__ Bm,
               void* __restrict__ Cv, int M, int N, int K) {
  __shared__ bf16_t As[128 * 32];
  __shared__ bf16_t Bs[128 * 32];
  const int tid = threadIdx.x;
  const int lane = tid & 63, wid = tid >> 6;
  const int l16 = lane & 15, lg = lane >> 4;
  const int row0 = blockIdx.x * 128, col0 = blockIdx.y * 128;
  const int wr = wid >> 1, wc = wid & 1;

  // staging coords: round r covers rows r*64 + wid*16 + lane/4, col (lane&3)*8
  const int s_row = wid * 16 + (lane >> 2);
  const int s_col = (lane & 3) * 8;
  const bf16_t* Ag = A  + (size_t)(row0 + s_row) * K + s_col;
  const bf16_t* Bg = Bm + (size_t)(col0 + s_row) * K + s_col;
  char* AsB = (char*)As + wid * 1024;
  char* BsB = (char*)Bs + wid * 1024;

  const int aoff0 = (wr * 64 + l16) * 32 + lg * 8;
  const int boff0 = (wc * 64 + l16) * 32 + lg * 8;

  f32x4 acc[4][4] = {};
  for (int kt = 0; kt < K; kt += 32) {
    gll16(Ag + kt,                 AsB);
    gll16(Ag + kt + (size_t)64 * K, AsB + 4096);
    gll16(Bg + kt,                 BsB);
    gll16(Bg + kt + (size_t)64 * K, BsB + 4096);
    __syncthreads();
    bf16x8 af[4], bfr[4];
#pragma unroll
    for (int m = 0; m < 4; ++m)
      af[m] = *reinterpret_cast<const bf16x8*>(&As[aoff0 + m * 512]);
#pragma unroll
    for (int n = 0; n < 4; ++n)
      bfr[n] = *reinterpret_cast<const bf16x8*>(&Bs[boff0 + n * 512]);
#pragma unroll
    for (int m = 0; m < 4; ++m)
#pragma unroll
      for (int n = 0; n < 4; ++n)
        acc[m][n] = __builtin_amdgcn_mfma_f32_16x16x32_bf16(af[m], bfr[n],
                                                            acc[m][n], 0, 0, 0);
    __syncthreads();
  }

  // C/D layout: col = lane&15, row = (lane>>4)*4 + j
  const int crow = row0 + wr * 64 + lg * 4;
  const int ccol = col0 + wc * 64 + l16;
#pragma unroll
  for (int m = 0; m < 4; ++m)
#pragma unroll
    for (int n = 0; n < 4; ++n)
#pragma unroll
      for (int j = 0; j < 4; ++j) {
        size_t idx = (size_t)(crow + m * 16 + j) * N + (ccol + n * 16);
        if constexpr (OUT_BF16)
          ((bf16_t*)Cv)[idx] = (__bf16)acc[m][n][j];
        else
          ((float*)Cv)[idx] = acc[m][n][j];
      }
}

// ---------------- flash attention (causal, GQA) ----------------------------
// 1 block = (b, h, 64-row Q tile); 4 waves x 16 q-rows. KBLK=64.
// K tile [64][128] and Vt tile [128][64] staged via global_load_lds with the
// pre-swizzled-source XOR trick (byte ^= (row&7)<<4) -> conflict-free b128 reads.
__global__ __launch_bounds__(256, 2)
void flash_k(const bf16_t* __restrict__ Qr, const bf16_t* __restrict__ Kr,
             const bf16_t* __restrict__ Vt, bf16_t* __restrict__ Ctx) {
  __shared__ bf16_t Ks[64 * 128];
  __shared__ bf16_t Vs[128 * 64];
  __shared__ bf16_t Ps[4][16][72];                     // per-wave P, pad 72

  const int bid = blockIdx.x;
  const int qt = bid & 31;
  const int h  = (bid >> 5) & 31;
  const int b  = bid >> 10;
  const int hkv = h >> 2;                              // G=4
  const int tid = threadIdx.x, lane = tid & 63, w = tid >> 6;
  const int l16 = lane & 15, lg = lane >> 4;

  // Q fragments in registers (rows w*16 + l16, scaled by 1/sqrt(DH) already)
  const bf16_t* Qg = Qr +
      ((size_t)(b * kH + h) * kT + qt * 64 + w * 16 + l16) * kDH + lg * 8;
  bf16x8 qf[4];
#pragma unroll
  for (int kk = 0; kk < 4; ++kk)
    qf[kk] = *reinterpret_cast<const bf16x8*>(Qg + kk * 32);

  const bf16_t* Kg = Kr + (size_t)(b * kHKV + hkv) * kT * kDH;
  const bf16_t* Vg = Vt + (size_t)(b * kHKV + hkv) * kDH * kT;

  // staging per-lane coords
  const int k_srow = w * 4 + lg;                       // + r*16 ; 256B rows
  const int k_scolb = l16 * 16;
  const int v_srow = w * 8 + (lane >> 3);              // + r*32 ; 128B rows
  const int v_scolb = (lane & 7) * 16;
  char* KsB = (char*)Ks + w * 1024;
  char* VsB = (char*)Vs + w * 1024;

  float m_run[4] = {-1e30f, -1e30f, -1e30f, -1e30f};
  float l_run[4] = {0.f, 0.f, 0.f, 0.f};
  f32x4 acc_o[8] = {};

  const int nkv = qt + 1;
  for (int it = 0; it < nkv; ++it) {
    const int kv0 = it * 64;
    // ---- stage K (16KB) and V (16KB), pre-swizzled source ----
#pragma unroll
    for (int r = 0; r < 4; ++r) {
      int krow = r * 16 + k_srow;
      int kcb  = k_scolb ^ ((krow & 7) << 4);
      gll16(Kg + (size_t)(kv0 + krow) * kDH + (kcb >> 1), KsB + r * 4096);
      int vrow = r * 32 + v_srow;
      int vcb  = v_scolb ^ ((vrow & 7) << 4);
      gll16(Vg + (size_t)vrow * kT + kv0 + (vcb >> 1), VsB + r * 4096);
    }
    __syncthreads();

    // ---- scores S = Q K^T ----
    f32x4 sc[4] = {};
#pragma unroll
    for (int kk = 0; kk < 4; ++kk) {
#pragma unroll
      for (int nf = 0; nf < 4; ++nf) {
        int row = nf * 16 + l16;
        int cb  = (kk * 64 + lg * 16) ^ ((row & 7) << 4);
        bf16x8 kf = *reinterpret_cast<const bf16x8*>((const char*)Ks + row * 256 + cb);
        sc[nf] = __builtin_amdgcn_mfma_f32_16x16x32_bf16(qf[kk], kf, sc[nf], 0, 0, 0);
      }
    }
    // ---- causal mask on diagonal tile ----
    if (it == qt) {
#pragma unroll
      for (int nf = 0; nf < 4; ++nf) {
        int key = kv0 + nf * 16 + l16;
#pragma unroll
        for (int j = 0; j < 4; ++j) {
          int qrow = qt * 64 + w * 16 + lg * 4 + j;
          if (key > qrow) sc[nf][j] = -1e30f;
        }
      }
    }
    // ---- online softmax (rows live in 16-lane groups; D row = lg*4+j) ----
#pragma unroll
    for (int j = 0; j < 4; ++j) {
      float mx = fmaxf(fmaxf(sc[0][j], sc[1][j]), fmaxf(sc[2][j], sc[3][j]));
      mx = fmaxf(mx, __shfl_xor(mx, 1));
      mx = fmaxf(mx, __shfl_xor(mx, 2));
      mx = fmaxf(mx, __shfl_xor(mx, 4));
      mx = fmaxf(mx, __shfl_xor(mx, 8));
      float mnew = fmaxf(m_run[j], mx);
      float alpha = __expf(m_run[j] - mnew);
      m_run[j] = mnew;
      float ssum = 0.f;
#pragma unroll
      for (int nf = 0; nf < 4; ++nf) {
        float p = __expf(sc[nf][j] - mnew);
        sc[nf][j] = p;
        ssum += p;
      }
      ssum += __shfl_xor(ssum, 1);
      ssum += __shfl_xor(ssum, 2);
      ssum += __shfl_xor(ssum, 4);
      ssum += __shfl_xor(ssum, 8);
      l_run[j] = l_run[j] * alpha + ssum;
#pragma unroll
      for (int nf = 0; nf < 8; ++nf) acc_o[nf][j] *= alpha;
    }
    // ---- P -> LDS (bf16), then PV ----
#pragma unroll
    for (int nf = 0; nf < 4; ++nf)
#pragma unroll
      for (int j = 0; j < 4; ++j)
        Ps[w][lg * 4 + j][nf * 16 + l16] = (__bf16)sc[nf][j];
    __syncthreads();                                   // also covers P visibility
#pragma unroll
    for (int kk2 = 0; kk2 < 2; ++kk2) {
      bf16x8 pf = *reinterpret_cast<const bf16x8*>(&Ps[w][l16][kk2 * 32 + lg * 8]);
#pragma unroll
      for (int nf = 0; nf < 8; ++nf) {
        int d = nf * 16 + l16;
        int cb = (kk2 * 64 + lg * 16) ^ ((d & 7) << 4);
        bf16x8 vf = *reinterpret_cast<const bf16x8*>((const char*)Vs + d * 128 + cb);
        acc_o[nf] = __builtin_amdgcn_mfma_f32_16x16x32_bf16(pf, vf, acc_o[nf], 0, 0, 0);
      }
    }
    __syncthreads();                                   // protect K/V restage
  }

  // ---- epilogue: ctx/l -> [B,T,H,DH] bf16 ----
  const int tglob = qt * 64 + w * 16 + lg * 4;
#pragma unroll
  for (int j = 0; j < 4; ++j) {
    float inv_l = 1.0f / l_run[j];
#pragma unroll
    for (int nf = 0; nf < 8; ++nf)
      Ctx[((size_t)(b * kT + tglob + j) * kH + h) * kDH + nf * 16 + l16] =
          (__bf16)(acc_o[nf][j] * inv_l);
  }
}

// ---------------------------------------------------------------------------
extern "C" void kernel_launch(void* const* d_in, const int* in_sizes, int n_in,
                              void* d_out, int out_size, void* d_ws, size_t ws_size,
                              hipStream_t stream) {
  (void)in_sizes; (void)n_in; (void)out_size; (void)ws_size;
  const float* x  = (const float*)d_in[0];
  const float* Wq = (const float*)d_in[1];
  const float* Wk = (const float*)d_in[2];
  const float* Wv = (const float*)d_in[3];
  const float* Wo = (const float*)d_in[4];
  float* out = (float*)d_out;

  char* ws = (char*)d_ws;
  size_t off = 0;
  auto alloc = [&](size_t bytes) -> char* {
    char* p = ws + off;
    off += (bytes + 255) & ~(size_t)255;
    return p;
  };
  bf16_t* xb    = (bf16_t*)alloc((size_t)kM * kE * 2);          // 33.5 MB
  bf16_t* Wqkvb = (bf16_t*)alloc((size_t)kNQKV * kE * 2);       // 50.3 MB
  bf16_t* Wob   = (bf16_t*)alloc((size_t)kE * kE * 2);          // 33.5 MB
  bf16_t* QKV   = (bf16_t*)alloc((size_t)kM * kNQKV * 2);       // 50.3 MB
  float*  cosT  = (float*)alloc((size_t)kT * 64 * 4);
  float*  sinT  = (float*)alloc((size_t)kT * 64 * 4);
  // aliases (dead-after-QKV-GEMM regions):
  bf16_t* Qr  = Wqkvb;                                          // [B,H,T,DH]
  bf16_t* Kr  = Wqkvb + (size_t)kE * kE;                        // [B,HKV,T,DH]
  bf16_t* Vt  = Wqkvb + (size_t)(kE + kHKV * kDH) * kE;         // [B,HKV,DH,T]
  bf16_t* Ctx = xb;                                             // [B,T,H,DH]

  // casts
  cast_f32_bf16_k<<<16384, 256, 0, stream>>>(x, xb, kM * kE / 4);
  cast_f32_bf16_k<<<16384, 256, 0, stream>>>(Wq, Wqkvb, kE * kE / 4);
  cast_f32_bf16_k<<<4096, 256, 0, stream>>>(Wk, Wqkvb + (size_t)kE * kE,
                                            kHKV * kDH * kE / 4);
  cast_f32_bf16_k<<<4096, 256, 0, stream>>>(Wv, Wqkvb + (size_t)(kE + kHKV * kDH) * kE,
                                            kHKV * kDH * kE / 4);
  cast_f32_bf16_k<<<16384, 256, 0, stream>>>(Wo, Wob, kE * kE / 4);
  rope_table_k<<<512, 256, 0, stream>>>(cosT, sinT);

  // fused QKV projection: [4096,6144] = xb @ Wqkvb^T
  {
    dim3 g(kM / 128, kNQKV / 128);
    gemm_nt_k<true><<<g, 256, 0, stream>>>(xb, Wqkvb, QKV, kM, kNQKV, kE);
  }
  // rope + layout
  rope_q_k<<<32768, 256, 0, stream>>>(QKV, cosT, sinT, Qr);
  rope_k_k<<<8192, 256, 0, stream>>>(QKV, cosT, sinT, Kr);
  vtrans_k<<<512, 256, 0, stream>>>(QKV, Vt);
  // attention
  flash_k<<<kB * kH * (kT / 64), 256, 0, stream>>>(Qr, Kr, Vt, Ctx);
  // output projection (fp32 out)
  {
    dim3 g(kM / 128, kE / 128);
    gemm_nt_k<false><<<g, 256, 0, stream>>>(Ctx, Wob, out, kM, kE, kE);
  }
}

// Round 2
// 854.793 us; speedup vs baseline: 1.0993x; 1.0993x over previous
//
#include <hip/hip_runtime.h>
#include <cstdint>
#include <cstddef>

// ---------------------------------------------------------------------------
// Llama3 MHA (B=2,T=2048,E=4096,H=32,HKV=8,DH=128), bf16 MFMA pipeline:
//   cast -> fused QKV NT-GEMM -> rope(q,k)+v-transpose -> flash attn -> O GEMM
// R1: flash rewritten — 128-row Q tile, double-buffered K/V with raw barrier +
//     counted vmcnt (stage-after-barrier), swizzled P tile, XCD-chunked +
//     heavy-first block order.
// ---------------------------------------------------------------------------

typedef __bf16 bf16_t;
typedef float  f32x4  __attribute__((ext_vector_type(4)));
typedef __bf16 bf16x8 __attribute__((ext_vector_type(8)));
typedef __bf16 bf16x4 __attribute__((ext_vector_type(4)));

static constexpr int kB   = 2;
static constexpr int kT   = 2048;
static constexpr int kE   = 4096;
static constexpr int kH   = 32;
static constexpr int kHKV = 8;
static constexpr int kDH  = 128;
static constexpr int kNQKV = kE + 2 * kHKV * kDH;   // 6144
static constexpr int kM    = kB * kT;               // 4096 rows

// async global->LDS, 16B per lane. LDS dest is wave-uniform base + lane*16.
__device__ __forceinline__ void gll16(const void* g, void* l) {
  __builtin_amdgcn_global_load_lds(
      (__attribute__((address_space(1))) void*)g,
      (__attribute__((address_space(3))) void*)l, 16, 0, 0);
}

// ---------------- fp32 -> bf16 cast (float4 vectorized) --------------------
__global__ void cast_f32_bf16_k(const float* __restrict__ in,
                                bf16_t* __restrict__ out, int n4) {
  int i = blockIdx.x * 256 + threadIdx.x;
  if (i >= n4) return;
  float4 v = reinterpret_cast<const float4*>(in)[i];
  bf16x4 o;
  o[0] = (__bf16)v.x; o[1] = (__bf16)v.y; o[2] = (__bf16)v.z; o[3] = (__bf16)v.w;
  reinterpret_cast<bf16x4*>(out)[i] = o;
}

// ---------------- rope cos/sin table (llama3 scaling, faithful port) -------
__global__ void rope_table_k(float* __restrict__ cosT, float* __restrict__ sinT) {
  int idx = blockIdx.x * 256 + threadIdx.x;            // T*64
  if (idx >= kT * 64) return;
  int t = idx >> 6, i = idx & 63;
  float ex  = (float)i / 64.0f;                         // arange(0,DH,2)/DH
  float inv = powf(500000.0f, -ex);
  float wl  = 6.283185307179586f / inv;
  const float cut_lo = 8192.0f / 4.0f;                  // 2048
  const float cut_hi = 8192.0f / 1.0f;                  // 8192
  float inv2 = (wl > cut_hi) ? inv * (1.0f / 32.0f) : inv;
  float smooth   = (8192.0f / wl - 1.0f) * (1.0f / 3.0f);
  float smoothed = (1.0f - smooth) * inv2 * (1.0f / 32.0f) + smooth * inv2;
  bool  medium   = (!(wl < cut_hi)) && (!(wl > cut_lo));  // always false (faithful)
  float invf = medium ? smoothed : inv2;
  float f = (float)t * invf;
  cosT[idx] = cosf(f);
  sinT[idx] = sinf(f);
}

// ---------------- rope on Q (+1/sqrt(DH) fold) , [B,T,H,DH]->[B,H,T,DH] ----
__global__ void rope_q_k(const bf16_t* __restrict__ QKV,
                         const float* __restrict__ cosT,
                         const float* __restrict__ sinT,
                         bf16_t* __restrict__ Qr) {
  int idx = blockIdx.x * 256 + threadIdx.x;            // B*T*H*64 = 2^23
  if (idx >= kB * kT * kH * 64) return;
  int i = idx & 63;
  int h = (idx >> 6) & 31;
  int t = (idx >> 11) & 2047;
  int b = idx >> 22;
  const bf16_t* src = QKV + (size_t)(b * kT + t) * kNQKV + h * kDH + i;
  float q1 = (float)src[0], q2 = (float)src[64];
  float c = cosT[(t << 6) + i], s = sinT[(t << 6) + i];
  const float sc = 0.08838834764831845f;               // 1/sqrt(128)
  bf16_t* dst = Qr + ((size_t)(b * kH + h) * kT + t) * kDH + i;
  dst[0]  = (__bf16)((q1 * c - q2 * s) * sc);
  dst[64] = (__bf16)((q2 * c + q1 * s) * sc);
}

// ---------------- rope on K, [B,T,HKV,DH]->[B,HKV,T,DH] --------------------
__global__ void rope_k_k(const bf16_t* __restrict__ QKV,
                         const float* __restrict__ cosT,
                         const float* __restrict__ sinT,
                         bf16_t* __restrict__ Kr) {
  int idx = blockIdx.x * 256 + threadIdx.x;            // B*T*HKV*64 = 2^21
  if (idx >= kB * kT * kHKV * 64) return;
  int i = idx & 63;
  int h = (idx >> 6) & 7;
  int t = (idx >> 9) & 2047;
  int b = idx >> 20;
  const bf16_t* src = QKV + (size_t)(b * kT + t) * kNQKV + kE + h * kDH + i;
  float k1 = (float)src[0], k2 = (float)src[64];
  float c = cosT[(t << 6) + i], s = sinT[(t << 6) + i];
  bf16_t* dst = Kr + ((size_t)(b * kHKV + h) * kT + t) * kDH + i;
  dst[0]  = (__bf16)(k1 * c - k2 * s);
  dst[64] = (__bf16)(k2 * c + k1 * s);
}

// ---------------- V transpose: [B,T,HKV,DH] -> Vt [B,HKV,DH,T] -------------
__global__ void vtrans_k(const bf16_t* __restrict__ QKV, bf16_t* __restrict__ Vt) {
  __shared__ bf16_t tile[64 * 130];                    // pad 130: conflict-free
  int bidx = blockIdx.x;                               // B*HKV*(T/64) = 512
  int tt = bidx & 31;
  int h  = (bidx >> 5) & 7;
  int b  = bidx >> 8;
  int tid = threadIdx.x;
  int t0 = tt * 64;
  for (int it = 0; it < 32; ++it) {
    int e = it * 256 + tid;
    int tr = e >> 7, d = e & 127;
    tile[tr * 130 + d] =
        QKV[(size_t)(b * kT + t0 + tr) * kNQKV + kE + kHKV * kDH + h * kDH + d];
  }
  __syncthreads();
  for (int j = 0; j < 32; ++j) {
    int o = j * 256 + tid;
    int d = o >> 6, tr = o & 63;
    Vt[((size_t)(b * kHKV + h) * kDH + d) * kT + t0 + tr] = tile[tr * 130 + d];
  }
}

// ---------------- NT GEMM: C[M,N] = A[M,K] * B[N,K]^T  (bf16, fp32 acc) ----
// m97 structure: 128x128 tile, BK=32, 4 waves, global_load_lds(16B), 2 barriers.
template <bool OUT_BF16>
__global__ __launch_bounds__(256, 2)
void gemm_nt_k(const bf16_t* __restrict__ A, const bf16_t* __restrict__ Bm,
               void* __restrict__ Cv, int M, int N, int K) {
  __shared__ bf16_t As[128 * 32];
  __shared__ bf16_t Bs[128 * 32];
  const int tid = threadIdx.x;
  const int lane = tid & 63, wid = tid >> 6;
  const int l16 = lane & 15, lg = lane >> 4;
  const int row0 = blockIdx.x * 128, col0 = blockIdx.y * 128;
  const int wr = wid >> 1, wc = wid & 1;

  const int s_row = wid * 16 + (lane >> 2);
  const int s_col = (lane & 3) * 8;
  const bf16_t* Ag = A  + (size_t)(row0 + s_row) * K + s_col;
  const bf16_t* Bg = Bm + (size_t)(col0 + s_row) * K + s_col;
  char* AsB = (char*)As + wid * 1024;
  char* BsB = (char*)Bs + wid * 1024;

  const int aoff0 = (wr * 64 + l16) * 32 + lg * 8;
  const int boff0 = (wc * 64 + l16) * 32 + lg * 8;

  f32x4 acc[4][4] = {};
  for (int kt = 0; kt < K; kt += 32) {
    gll16(Ag + kt,                 AsB);
    gll16(Ag + kt + (size_t)64 * K, AsB + 4096);
    gll16(Bg + kt,                 BsB);
    gll16(Bg + kt + (size_t)64 * K, BsB + 4096);
    __syncthreads();
    bf16x8 af[4], bfr[4];
#pragma unroll
    for (int m = 0; m < 4; ++m)
      af[m] = *reinterpret_cast<const bf16x8*>(&As[aoff0 + m * 512]);
#pragma unroll
    for (int n = 0; n < 4; ++n)
      bfr[n] = *reinterpret_cast<const bf16x8*>(&Bs[boff0 + n * 512]);
#pragma unroll
    for (int m = 0; m < 4; ++m)
#pragma unroll
      for (int n = 0; n < 4; ++n)
        acc[m][n] = __builtin_amdgcn_mfma_f32_16x16x32_bf16(af[m], bfr[n],
                                                            acc[m][n], 0, 0, 0);
    __syncthreads();
  }

  const int crow = row0 + wr * 64 + lg * 4;
  const int ccol = col0 + wc * 64 + l16;
#pragma unroll
  for (int m = 0; m < 4; ++m)
#pragma unroll
    for (int n = 0; n < 4; ++n)
#pragma unroll
      for (int j = 0; j < 4; ++j) {
        size_t idx = (size_t)(crow + m * 16 + j) * N + (ccol + n * 16);
        if constexpr (OUT_BF16)
          ((bf16_t*)Cv)[idx] = (__bf16)acc[m][n][j];
        else
          ((float*)Cv)[idx] = acc[m][n][j];
      }
}

// ---------------- flash attention (causal, GQA) ----------------------------
// 1 block = (b, h, 128-row Q tile); 4 waves x 32 q-rows. KBLK=64, dbuf K/V.
// One raw s_barrier per KV-iter; stage(t+1) issued AFTER the barrier so its
// loads fly under compute(t); vmcnt(0) at top of next iter is then ~free.
// K [64][128], Vt [128][64], P [32][64] all XOR-swizzled (byte ^= (row&7)<<4).
__global__ __launch_bounds__(256, 2)
void flash_k(const bf16_t* __restrict__ Qr, const bf16_t* __restrict__ Kr,
             const bf16_t* __restrict__ Vt, bf16_t* __restrict__ Ctx) {
  __shared__ bf16_t Ks[2][64 * 128];
  __shared__ bf16_t Vs[2][128 * 64];
  __shared__ bf16_t Ps[4][32 * 64];

  // XCD-chunked (bijective: 1024 = 8*128) + heavy-qt-first mapping
  const int gid  = blockIdx.x;
  const int wgid = (gid & 7) * 128 + (gid >> 3);
  const int qt = 15 - (wgid & 15);                     // heavy tiles first
  const int h  = (wgid >> 4) & 31;
  const int b  = wgid >> 9;
  const int hkv = h >> 2;                              // G=4
  const int tid = threadIdx.x, lane = tid & 63, w = tid >> 6;
  const int l16 = lane & 15, lg = lane >> 4;
  const int qbase = qt * 128;

  // Q fragments in registers: wave rows w*32 + m*16 + l16 (pre-scaled)
  const bf16_t* Qg = Qr +
      ((size_t)(b * kH + h) * kT + qbase + w * 32 + l16) * kDH + lg * 8;
  bf16x8 qf[2][4];
#pragma unroll
  for (int m = 0; m < 2; ++m)
#pragma unroll
    for (int kk = 0; kk < 4; ++kk)
      qf[m][kk] = *reinterpret_cast<const bf16x8*>(Qg + m * 16 * kDH + kk * 32);

  const bf16_t* Kg = Kr + (size_t)(b * kHKV + hkv) * kT * kDH;
  const bf16_t* Vg = Vt + (size_t)(b * kHKV + hkv) * kDH * kT;

  // staging per-lane coords (LDS dest is linear: base + lane*16)
  const int k_srow = w * 4 + lg;                       // + r*16 ; 256B rows
  const int k_scolb = l16 * 16;
  const int v_srow = w * 8 + (lane >> 3);              // + r*32 ; 128B rows
  const int v_scolb = (lane & 7) * 16;

  float m_run[2][4], l_run[2][4];
#pragma unroll
  for (int m = 0; m < 2; ++m)
#pragma unroll
    for (int j = 0; j < 4; ++j) { m_run[m][j] = -1e30f; l_run[m][j] = 0.f; }
  f32x4 acc_o[2][8] = {};

  const int nkv = 2 * qt + 2;

  // prologue: stage tile 0 into buffer 0
#pragma unroll
  for (int r = 0; r < 4; ++r) {
    int krow = r * 16 + k_srow;
    int kcb  = k_scolb ^ ((krow & 7) << 4);
    gll16(Kg + (size_t)krow * kDH + (kcb >> 1),
          (char*)Ks[0] + w * 1024 + r * 4096);
    int vrow = r * 32 + v_srow;
    int vcb  = v_scolb ^ ((vrow & 7) << 4);
    gll16(Vg + (size_t)vrow * kT + (vcb >> 1),
          (char*)Vs[0] + w * 1024 + r * 4096);
  }

  for (int it = 0; it < nkv; ++it) {
    const int cur = it & 1;
    const int kv0 = it * 64;
    // stage(it) was issued one compute-phase ago -> this wait is ~free
    asm volatile("s_waitcnt vmcnt(0)" ::: "memory");
    __builtin_amdgcn_s_barrier();
    __builtin_amdgcn_sched_barrier(0);
    // prefetch tile it+1 into the other buffer (safe: all waves are past
    // their reads of that buffer, enforced by the barrier above)
    if (it + 1 < nkv) {
      const int kv1 = kv0 + 64;
#pragma unroll
      for (int r = 0; r < 4; ++r) {
        int krow = r * 16 + k_srow;
        int kcb  = k_scolb ^ ((krow & 7) << 4);
        gll16(Kg + (size_t)(kv1 + krow) * kDH + (kcb >> 1),
              (char*)Ks[cur ^ 1] + w * 1024 + r * 4096);
        int vrow = r * 32 + v_srow;
        int vcb  = v_scolb ^ ((vrow & 7) << 4);
        gll16(Vg + (size_t)vrow * kT + kv1 + (vcb >> 1),
              (char*)Vs[cur ^ 1] + w * 1024 + r * 4096);
      }
    }

    // ---- scores S = Q K^T  (2 m-frags x 4 nf) ----
    f32x4 sc[2][4] = {};
#pragma unroll
    for (int kk = 0; kk < 4; ++kk) {
#pragma unroll
      for (int nf = 0; nf < 4; ++nf) {
        int row = nf * 16 + l16;
        int cb  = (kk * 64 + lg * 16) ^ ((row & 7) << 4);
        bf16x8 kf = *reinterpret_cast<const bf16x8*>(
            (const char*)Ks[cur] + row * 256 + cb);
#pragma unroll
        for (int m = 0; m < 2; ++m)
          sc[m][nf] = __builtin_amdgcn_mfma_f32_16x16x32_bf16(
              qf[m][kk], kf, sc[m][nf], 0, 0, 0);
      }
    }
    // ---- causal mask (last two tiles contain the diagonal) ----
    if (it >= nkv - 2) {
#pragma unroll
      for (int nf = 0; nf < 4; ++nf) {
        int key = kv0 + nf * 16 + l16;
#pragma unroll
        for (int m = 0; m < 2; ++m)
#pragma unroll
          for (int j = 0; j < 4; ++j) {
            int qrow = qbase + w * 32 + m * 16 + lg * 4 + j;
            if (key > qrow) sc[m][nf][j] = -1e30f;
          }
      }
    }
    // ---- online softmax (keys live across l16 lanes; 8 independent chains)
#pragma unroll
    for (int m = 0; m < 2; ++m)
#pragma unroll
      for (int j = 0; j < 4; ++j) {
        float mx = fmaxf(fmaxf(sc[m][0][j], sc[m][1][j]),
                         fmaxf(sc[m][2][j], sc[m][3][j]));
        mx = fmaxf(mx, __shfl_xor(mx, 1));
        mx = fmaxf(mx, __shfl_xor(mx, 2));
        mx = fmaxf(mx, __shfl_xor(mx, 4));
        mx = fmaxf(mx, __shfl_xor(mx, 8));
        float mnew = fmaxf(m_run[m][j], mx);
        float alpha = __expf(m_run[m][j] - mnew);
        m_run[m][j] = mnew;
        float ssum = 0.f;
#pragma unroll
        for (int nf = 0; nf < 4; ++nf) {
          float p = __expf(sc[m][nf][j] - mnew);
          sc[m][nf][j] = p;
          ssum += p;
        }
        ssum += __shfl_xor(ssum, 1);
        ssum += __shfl_xor(ssum, 2);
        ssum += __shfl_xor(ssum, 4);
        ssum += __shfl_xor(ssum, 8);
        l_run[m][j] = l_run[m][j] * alpha + ssum;
#pragma unroll
        for (int nf = 0; nf < 8; ++nf) acc_o[m][nf][j] *= alpha;
      }
    // ---- P -> LDS (bf16, XOR-swizzled rows), per-wave region ----
#pragma unroll
    for (int m = 0; m < 2; ++m)
#pragma unroll
      for (int j = 0; j < 4; ++j) {
        int prow = m * 16 + lg * 4 + j;
        int swz  = (prow & 7) << 4;
#pragma unroll
        for (int nf = 0; nf < 4; ++nf) {
          int wbyte = ((nf * 16 + l16) * 2) ^ swz;
          *(bf16_t*)((char*)Ps[w] + prow * 128 + wbyte) = (__bf16)sc[m][nf][j];
        }
      }
    // LDS ops from one wave execute in order -> no barrier needed (per-wave P)
    // ---- PV ----
#pragma unroll
    for (int kk2 = 0; kk2 < 2; ++kk2) {
      bf16x8 pf[2];
#pragma unroll
      for (int m = 0; m < 2; ++m) {
        int prow = m * 16 + l16;
        int cb = (kk2 * 64 + lg * 16) ^ ((prow & 7) << 4);
        pf[m] = *reinterpret_cast<const bf16x8*>(
            (const char*)Ps[w] + prow * 128 + cb);
      }
#pragma unroll
      for (int nf = 0; nf < 8; ++nf) {
        int d = nf * 16 + l16;
        int cb = (kk2 * 64 + lg * 16) ^ ((d & 7) << 4);
        bf16x8 vf = *reinterpret_cast<const bf16x8*>(
            (const char*)Vs[cur] + d * 128 + cb);
#pragma unroll
        for (int m = 0; m < 2; ++m)
          acc_o[m][nf] = __builtin_amdgcn_mfma_f32_16x16x32_bf16(
              pf[m], vf, acc_o[m][nf], 0, 0, 0);
      }
    }
  }

  // ---- epilogue: ctx/l -> [B,T,H,DH] bf16 ----
#pragma unroll
  for (int m = 0; m < 2; ++m) {
    const int tglob = qbase + w * 32 + m * 16 + lg * 4;
#pragma unroll
    for (int j = 0; j < 4; ++j) {
      float inv_l = 1.0f / l_run[m][j];
#pragma unroll
      for (int nf = 0; nf < 8; ++nf)
        Ctx[((size_t)(b * kT + tglob + j) * kH + h) * kDH + nf * 16 + l16] =
            (__bf16)(acc_o[m][nf][j] * inv_l);
    }
  }
}

// ---------------------------------------------------------------------------
extern "C" void kernel_launch(void* const* d_in, const int* in_sizes, int n_in,
                              void* d_out, int out_size, void* d_ws, size_t ws_size,
                              hipStream_t stream) {
  (void)in_sizes; (void)n_in; (void)out_size; (void)ws_size;
  const float* x  = (const float*)d_in[0];
  const float* Wq = (const float*)d_in[1];
  const float* Wk = (const float*)d_in[2];
  const float* Wv = (const float*)d_in[3];
  const float* Wo = (const float*)d_in[4];
  float* out = (float*)d_out;

  char* ws = (char*)d_ws;
  size_t off = 0;
  auto alloc = [&](size_t bytes) -> char* {
    char* p = ws + off;
    off += (bytes + 255) & ~(size_t)255;
    return p;
  };
  bf16_t* xb    = (bf16_t*)alloc((size_t)kM * kE * 2);          // 33.5 MB
  bf16_t* Wqkvb = (bf16_t*)alloc((size_t)kNQKV * kE * 2);       // 50.3 MB
  bf16_t* Wob   = (bf16_t*)alloc((size_t)kE * kE * 2);          // 33.5 MB
  bf16_t* QKV   = (bf16_t*)alloc((size_t)kM * kNQKV * 2);       // 50.3 MB
  float*  cosT  = (float*)alloc((size_t)kT * 64 * 4);
  float*  sinT  = (float*)alloc((size_t)kT * 64 * 4);
  // aliases (dead-after-QKV-GEMM regions):
  bf16_t* Qr  = Wqkvb;                                          // [B,H,T,DH]
  bf16_t* Kr  = Wqkvb + (size_t)kE * kE;                        // [B,HKV,T,DH]
  bf16_t* Vt  = Wqkvb + (size_t)(kE + kHKV * kDH) * kE;         // [B,HKV,DH,T]
  bf16_t* Ctx = xb;                                             // [B,T,H,DH]

  // casts
  cast_f32_bf16_k<<<16384, 256, 0, stream>>>(x, xb, kM * kE / 4);
  cast_f32_bf16_k<<<16384, 256, 0, stream>>>(Wq, Wqkvb, kE * kE / 4);
  cast_f32_bf16_k<<<4096, 256, 0, stream>>>(Wk, Wqkvb + (size_t)kE * kE,
                                            kHKV * kDH * kE / 4);
  cast_f32_bf16_k<<<4096, 256, 0, stream>>>(Wv, Wqkvb + (size_t)(kE + kHKV * kDH) * kE,
                                            kHKV * kDH * kE / 4);
  cast_f32_bf16_k<<<16384, 256, 0, stream>>>(Wo, Wob, kE * kE / 4);
  rope_table_k<<<512, 256, 0, stream>>>(cosT, sinT);

  // fused QKV projection: [4096,6144] = xb @ Wqkvb^T
  {
    dim3 g(kM / 128, kNQKV / 128);
    gemm_nt_k<true><<<g, 256, 0, stream>>>(xb, Wqkvb, QKV, kM, kNQKV, kE);
  }
  // rope + layout
  rope_q_k<<<32768, 256, 0, stream>>>(QKV, cosT, sinT, Qr);
  rope_k_k<<<8192, 256, 0, stream>>>(QKV, cosT, sinT, Kr);
  vtrans_k<<<512, 256, 0, stream>>>(QKV, Vt);
  // attention: B*H*(T/128) = 1024 blocks
  flash_k<<<kB * kH * (kT / 128), 256, 0, stream>>>(Qr, Kr, Vt, Ctx);
  // output projection (fp32 out)
  {
    dim3 g(kM / 128, kE / 128);
    gemm_nt_k<false><<<g, 256, 0, stream>>>(Ctx, Wob, out, kM, kE, kE);
  }
}

// Round 3
// 813.439 us; speedup vs baseline: 1.1551x; 1.0508x over previous
//
#include <hip/hip_runtime.h>
#include <cstdint>
#include <cstddef>

// ---------------------------------------------------------------------------
// Llama3 MHA (B=2,T=2048,E=4096,H=32,HKV=8,DH=128), bf16 MFMA pipeline:
//   cast -> fused QKV NT-GEMM -> rope(q,k)+v-transpose -> flash attn -> O GEMM
// R1: flash rewritten (128-row Q tile, dbuf K/V, stage-after-barrier).
// R2: GEMM rewritten — 256x256 tile, BK=32, 4-deep LDS pipeline with counted
//     vmcnt(8) (never drain), ONE fused waitcnt+barrier per K-tile, XOR
//     bank-swizzle (source-side for global_load_lds + read-side), setprio,
//     XCD-chunked col-major block remap. 128KB dynamic LDS.
// ---------------------------------------------------------------------------

typedef __bf16 bf16_t;
typedef float  f32x4  __attribute__((ext_vector_type(4)));
typedef __bf16 bf16x8 __attribute__((ext_vector_type(8)));
typedef __bf16 bf16x4 __attribute__((ext_vector_type(4)));

static constexpr int kB   = 2;
static constexpr int kT   = 2048;
static constexpr int kE   = 4096;
static constexpr int kH   = 32;
static constexpr int kHKV = 8;
static constexpr int kDH  = 128;
static constexpr int kNQKV = kE + 2 * kHKV * kDH;   // 6144
static constexpr int kM    = kB * kT;               // 4096 rows

// async global->LDS, 16B per lane. LDS dest is wave-uniform base + lane*16.
__device__ __forceinline__ void gll16(const void* g, void* l) {
  __builtin_amdgcn_global_load_lds(
      (__attribute__((address_space(1))) void*)g,
      (__attribute__((address_space(3))) void*)l, 16, 0, 0);
}

// ---------------- fp32 -> bf16 cast (float4 vectorized) --------------------
__global__ void cast_f32_bf16_k(const float* __restrict__ in,
                                bf16_t* __restrict__ out, int n4) {
  int i = blockIdx.x * 256 + threadIdx.x;
  if (i >= n4) return;
  float4 v = reinterpret_cast<const float4*>(in)[i];
  bf16x4 o;
  o[0] = (__bf16)v.x; o[1] = (__bf16)v.y; o[2] = (__bf16)v.z; o[3] = (__bf16)v.w;
  reinterpret_cast<bf16x4*>(out)[i] = o;
}

// ---------------- rope cos/sin table (llama3 scaling, faithful port) -------
__global__ void rope_table_k(float* __restrict__ cosT, float* __restrict__ sinT) {
  int idx = blockIdx.x * 256 + threadIdx.x;            // T*64
  if (idx >= kT * 64) return;
  int t = idx >> 6, i = idx & 63;
  float ex  = (float)i / 64.0f;                         // arange(0,DH,2)/DH
  float inv = powf(500000.0f, -ex);
  float wl  = 6.283185307179586f / inv;
  const float cut_lo = 8192.0f / 4.0f;                  // 2048
  const float cut_hi = 8192.0f / 1.0f;                  // 8192
  float inv2 = (wl > cut_hi) ? inv * (1.0f / 32.0f) : inv;
  float smooth   = (8192.0f / wl - 1.0f) * (1.0f / 3.0f);
  float smoothed = (1.0f - smooth) * inv2 * (1.0f / 32.0f) + smooth * inv2;
  bool  medium   = (!(wl < cut_hi)) && (!(wl > cut_lo));  // always false (faithful)
  float invf = medium ? smoothed : inv2;
  float f = (float)t * invf;
  cosT[idx] = cosf(f);
  sinT[idx] = sinf(f);
}

// ---------------- rope on Q (+1/sqrt(DH) fold) , [B,T,H,DH]->[B,H,T,DH] ----
__global__ void rope_q_k(const bf16_t* __restrict__ QKV,
                         const float* __restrict__ cosT,
                         const float* __restrict__ sinT,
                         bf16_t* __restrict__ Qr) {
  int idx = blockIdx.x * 256 + threadIdx.x;            // B*T*H*64 = 2^23
  if (idx >= kB * kT * kH * 64) return;
  int i = idx & 63;
  int h = (idx >> 6) & 31;
  int t = (idx >> 11) & 2047;
  int b = idx >> 22;
  const bf16_t* src = QKV + (size_t)(b * kT + t) * kNQKV + h * kDH + i;
  float q1 = (float)src[0], q2 = (float)src[64];
  float c = cosT[(t << 6) + i], s = sinT[(t << 6) + i];
  const float sc = 0.08838834764831845f;               // 1/sqrt(128)
  bf16_t* dst = Qr + ((size_t)(b * kH + h) * kT + t) * kDH + i;
  dst[0]  = (__bf16)((q1 * c - q2 * s) * sc);
  dst[64] = (__bf16)((q2 * c + q1 * s) * sc);
}

// ---------------- rope on K, [B,T,HKV,DH]->[B,HKV,T,DH] --------------------
__global__ void rope_k_k(const bf16_t* __restrict__ QKV,
                         const float* __restrict__ cosT,
                         const float* __restrict__ sinT,
                         bf16_t* __restrict__ Kr) {
  int idx = blockIdx.x * 256 + threadIdx.x;            // B*T*HKV*64 = 2^21
  if (idx >= kB * kT * kHKV * 64) return;
  int i = idx & 63;
  int h = (idx >> 6) & 7;
  int t = (idx >> 9) & 2047;
  int b = idx >> 20;
  const bf16_t* src = QKV + (size_t)(b * kT + t) * kNQKV + kE + h * kDH + i;
  float k1 = (float)src[0], k2 = (float)src[64];
  float c = cosT[(t << 6) + i], s = sinT[(t << 6) + i];
  bf16_t* dst = Kr + ((size_t)(b * kHKV + h) * kT + t) * kDH + i;
  dst[0]  = (__bf16)(k1 * c - k2 * s);
  dst[64] = (__bf16)(k2 * c + k1 * s);
}

// ---------------- V transpose: [B,T,HKV,DH] -> Vt [B,HKV,DH,T] -------------
__global__ void vtrans_k(const bf16_t* __restrict__ QKV, bf16_t* __restrict__ Vt) {
  __shared__ bf16_t tile[64 * 130];                    // pad 130: conflict-free
  int bidx = blockIdx.x;                               // B*HKV*(T/64) = 512
  int tt = bidx & 31;
  int h  = (bidx >> 5) & 7;
  int b  = bidx >> 8;
  int tid = threadIdx.x;
  int t0 = tt * 64;
  for (int it = 0; it < 32; ++it) {
    int e = it * 256 + tid;
    int tr = e >> 7, d = e & 127;
    tile[tr * 130 + d] =
        QKV[(size_t)(b * kT + t0 + tr) * kNQKV + kE + kHKV * kDH + h * kDH + d];
  }
  __syncthreads();
  for (int j = 0; j < 32; ++j) {
    int o = j * 256 + tid;
    int d = o >> 6, tr = o & 63;
    Vt[((size_t)(b * kHKV + h) * kDH + d) * kT + t0 + tr] = tile[tr * 130 + d];
  }
}

// ---------------- NT GEMM: C[M,N] = A[M,K] * B[N,K]^T  (bf16, fp32 acc) ----
// 256x256 tile, BK=32, 8 waves (2x4, per-wave 128x64), 4-deep LDS pipeline:
// prefetch distance 3, counted vmcnt(8) fused with s_barrier (ONE barrier per
// K-tile, never drains). LDS 4x(16K A + 16K B) = 128KB dynamic.
// Bank swizzle: phys_byte = logical ^ (((logical>>7)&3)<<4)  (involution;
// applied to the global SOURCE of global_load_lds and to ds_read addrs).
// M is always 4096 -> 16 row-tiles (hardcoded shift in block remap).
template <bool OUT_BF16>
__global__ __launch_bounds__(512, 2)
void gemm_nt_k(const bf16_t* __restrict__ A, const bf16_t* __restrict__ Bm,
               void* __restrict__ Cv, int M, int N, int K) {
  extern __shared__ char smem[];
  const int tid = threadIdx.x;
  const int lane = tid & 63, wid = tid >> 6;
  const int l16 = lane & 15, lg = lane >> 4;
  const int wm = wid >> 2, wn = wid & 3;

  // XCD-chunked (grid divisible by 8: 384 / 256) + column-panel-major
  const int nwg = gridDim.x;
  const int bid = blockIdx.x;
  const int wg = (bid & 7) * (nwg >> 3) + (bid >> 3);
  const int colT = wg >> 4, rowT = wg & 15;            // gM = 4096/256 = 16
  const int row0 = rowT * 256, col0 = colT * 256;

  // staging source addresses (inverse-swizzled so linear LDS dest ends up
  // holding the swizzled layout). Phys byte P in 16KB tile: row=P>>6 (64B
  // rows), kbyte=(P&63)^(((P>>7)&3)<<4).
  const int P0 = (wid << 10) + (lane << 4);
  const int P1 = P0 + 8192;
  const int r0 = P0 >> 6, kb0 = (P0 & 63) ^ (((P0 >> 7) & 3) << 4);
  const int r1 = P1 >> 6, kb1 = (P1 & 63) ^ (((P1 >> 7) & 3) << 4);
  const bf16_t* Ag0 = A  + (size_t)(row0 + r0) * K + (kb0 >> 1);
  const bf16_t* Ag1 = A  + (size_t)(row0 + r1) * K + (kb1 >> 1);
  const bf16_t* Bg0 = Bm + (size_t)(col0 + r0) * K + (kb0 >> 1);
  const bf16_t* Bg1 = Bm + (size_t)(col0 + r1) * K + (kb1 >> 1);

  char* const AsBase = smem;                           // 4 x 16KB
  char* const BsBase = smem + 65536;                   // 4 x 16KB
  const int woff = wid << 10;

  auto stage = [&](int t, int b) {
    const int kt = t << 5;                             // elements
    char* As = AsBase + (b << 14);
    char* Bs = BsBase + (b << 14);
    gll16(Ag0 + kt, As + woff);
    gll16(Ag1 + kt, As + 8192 + woff);
    gll16(Bg0 + kt, Bs + woff);
    gll16(Bg1 + kt, Bs + 8192 + woff);
  };

  // swizzled read byte-offsets (within a 16KB tile)
  int aoffB[8], boffB[4];
#pragma unroll
  for (int m = 0; m < 8; ++m) {
    int r = wm * 128 + m * 16 + l16;
    aoffB[m] = r * 64 + ((lg ^ ((r >> 1) & 3)) << 4);
  }
#pragma unroll
  for (int n = 0; n < 4; ++n) {
    int r = wn * 64 + n * 16 + l16;
    boffB[n] = r * 64 + ((lg ^ ((r >> 1) & 3)) << 4);
  }

  f32x4 acc[8][4] = {};
  const int NT = K >> 5;                               // 128

  stage(0, 0); stage(1, 1); stage(2, 2);               // 12 loads in flight

  for (int t = 0; t < NT; ++t) {
    // tile t guaranteed landed (own loads) -> barrier propagates to all waves;
    // same barrier proves everyone finished reading tile t-1 (its buffer is
    // the prefetch target below). Tiles t+1,t+2 (8 loads) stay in flight.
    asm volatile("s_waitcnt vmcnt(8)\n\ts_barrier" ::: "memory");
    __builtin_amdgcn_sched_barrier(0);
    const int tp = t + 3;                              // clamped tail re-stage
    stage(tp < NT ? tp : NT - 1, tp & 3);              // keeps vmcnt math fixed
    __builtin_amdgcn_sched_barrier(0);

    const char* As = AsBase + ((t & 3) << 14);
    const char* Bs = BsBase + ((t & 3) << 14);
    bf16x8 af[8], bf[4];
#pragma unroll
    for (int m = 0; m < 8; ++m)
      af[m] = *reinterpret_cast<const bf16x8*>(As + aoffB[m]);
#pragma unroll
    for (int n = 0; n < 4; ++n)
      bf[n] = *reinterpret_cast<const bf16x8*>(Bs + boffB[n]);
    __builtin_amdgcn_s_setprio(1);
#pragma unroll
    for (int m = 0; m < 8; ++m)
#pragma unroll
      for (int n = 0; n < 4; ++n)
        acc[m][n] = __builtin_amdgcn_mfma_f32_16x16x32_bf16(af[m], bf[n],
                                                            acc[m][n], 0, 0, 0);
    __builtin_amdgcn_s_setprio(0);
    __builtin_amdgcn_sched_barrier(0);
  }
  asm volatile("s_waitcnt vmcnt(0)" ::: "memory");     // drain tail re-stages

  // epilogue: C/D layout col = lane&15, row = (lane>>4)*4 + j
  const int crow = row0 + wm * 128 + lg * 4;
  const int ccol = col0 + wn * 64 + l16;
#pragma unroll
  for (int m = 0; m < 8; ++m)
#pragma unroll
    for (int n = 0; n < 4; ++n)
#pragma unroll
      for (int j = 0; j < 4; ++j) {
        size_t idx = (size_t)(crow + m * 16 + j) * N + (ccol + n * 16);
        if constexpr (OUT_BF16)
          ((bf16_t*)Cv)[idx] = (__bf16)acc[m][n][j];
        else
          ((float*)Cv)[idx] = acc[m][n][j];
      }
}

// ---------------- flash attention (causal, GQA) ----------------------------
// 1 block = (b, h, 128-row Q tile); 4 waves x 32 q-rows. KBLK=64, dbuf K/V.
__global__ __launch_bounds__(256, 2)
void flash_k(const bf16_t* __restrict__ Qr, const bf16_t* __restrict__ Kr,
             const bf16_t* __restrict__ Vt, bf16_t* __restrict__ Ctx) {
  __shared__ bf16_t Ks[2][64 * 128];
  __shared__ bf16_t Vs[2][128 * 64];
  __shared__ bf16_t Ps[4][32 * 64];

  const int gid  = blockIdx.x;
  const int wgid = (gid & 7) * 128 + (gid >> 3);
  const int qt = 15 - (wgid & 15);                     // heavy tiles first
  const int h  = (wgid >> 4) & 31;
  const int b  = wgid >> 9;
  const int hkv = h >> 2;                              // G=4
  const int tid = threadIdx.x, lane = tid & 63, w = tid >> 6;
  const int l16 = lane & 15, lg = lane >> 4;
  const int qbase = qt * 128;

  const bf16_t* Qg = Qr +
      ((size_t)(b * kH + h) * kT + qbase + w * 32 + l16) * kDH + lg * 8;
  bf16x8 qf[2][4];
#pragma unroll
  for (int m = 0; m < 2; ++m)
#pragma unroll
    for (int kk = 0; kk < 4; ++kk)
      qf[m][kk] = *reinterpret_cast<const bf16x8*>(Qg + m * 16 * kDH + kk * 32);

  const bf16_t* Kg = Kr + (size_t)(b * kHKV + hkv) * kT * kDH;
  const bf16_t* Vg = Vt + (size_t)(b * kHKV + hkv) * kDH * kT;

  const int k_srow = w * 4 + lg;                       // + r*16 ; 256B rows
  const int k_scolb = l16 * 16;
  const int v_srow = w * 8 + (lane >> 3);              // + r*32 ; 128B rows
  const int v_scolb = (lane & 7) * 16;

  float m_run[2][4], l_run[2][4];
#pragma unroll
  for (int m = 0; m < 2; ++m)
#pragma unroll
    for (int j = 0; j < 4; ++j) { m_run[m][j] = -1e30f; l_run[m][j] = 0.f; }
  f32x4 acc_o[2][8] = {};

  const int nkv = 2 * qt + 2;

#pragma unroll
  for (int r = 0; r < 4; ++r) {
    int krow = r * 16 + k_srow;
    int kcb  = k_scolb ^ ((krow & 7) << 4);
    gll16(Kg + (size_t)krow * kDH + (kcb >> 1),
          (char*)Ks[0] + w * 1024 + r * 4096);
    int vrow = r * 32 + v_srow;
    int vcb  = v_scolb ^ ((vrow & 7) << 4);
    gll16(Vg + (size_t)vrow * kT + (vcb >> 1),
          (char*)Vs[0] + w * 1024 + r * 4096);
  }

  for (int it = 0; it < nkv; ++it) {
    const int cur = it & 1;
    const int kv0 = it * 64;
    asm volatile("s_waitcnt vmcnt(0)" ::: "memory");
    __builtin_amdgcn_s_barrier();
    __builtin_amdgcn_sched_barrier(0);
    if (it + 1 < nkv) {
      const int kv1 = kv0 + 64;
#pragma unroll
      for (int r = 0; r < 4; ++r) {
        int krow = r * 16 + k_srow;
        int kcb  = k_scolb ^ ((krow & 7) << 4);
        gll16(Kg + (size_t)(kv1 + krow) * kDH + (kcb >> 1),
              (char*)Ks[cur ^ 1] + w * 1024 + r * 4096);
        int vrow = r * 32 + v_srow;
        int vcb  = v_scolb ^ ((vrow & 7) << 4);
        gll16(Vg + (size_t)vrow * kT + kv1 + (vcb >> 1),
              (char*)Vs[cur ^ 1] + w * 1024 + r * 4096);
      }
    }

    f32x4 sc[2][4] = {};
#pragma unroll
    for (int kk = 0; kk < 4; ++kk) {
#pragma unroll
      for (int nf = 0; nf < 4; ++nf) {
        int row = nf * 16 + l16;
        int cb  = (kk * 64 + lg * 16) ^ ((row & 7) << 4);
        bf16x8 kf = *reinterpret_cast<const bf16x8*>(
            (const char*)Ks[cur] + row * 256 + cb);
#pragma unroll
        for (int m = 0; m < 2; ++m)
          sc[m][nf] = __builtin_amdgcn_mfma_f32_16x16x32_bf16(
              qf[m][kk], kf, sc[m][nf], 0, 0, 0);
      }
    }
    if (it >= nkv - 2) {
#pragma unroll
      for (int nf = 0; nf < 4; ++nf) {
        int key = kv0 + nf * 16 + l16;
#pragma unroll
        for (int m = 0; m < 2; ++m)
#pragma unroll
          for (int j = 0; j < 4; ++j) {
            int qrow = qbase + w * 32 + m * 16 + lg * 4 + j;
            if (key > qrow) sc[m][nf][j] = -1e30f;
          }
      }
    }
#pragma unroll
    for (int m = 0; m < 2; ++m)
#pragma unroll
      for (int j = 0; j < 4; ++j) {
        float mx = fmaxf(fmaxf(sc[m][0][j], sc[m][1][j]),
                         fmaxf(sc[m][2][j], sc[m][3][j]));
        mx = fmaxf(mx, __shfl_xor(mx, 1));
        mx = fmaxf(mx, __shfl_xor(mx, 2));
        mx = fmaxf(mx, __shfl_xor(mx, 4));
        mx = fmaxf(mx, __shfl_xor(mx, 8));
        float mnew = fmaxf(m_run[m][j], mx);
        float alpha = __expf(m_run[m][j] - mnew);
        m_run[m][j] = mnew;
        float ssum = 0.f;
#pragma unroll
        for (int nf = 0; nf < 4; ++nf) {
          float p = __expf(sc[m][nf][j] - mnew);
          sc[m][nf][j] = p;
          ssum += p;
        }
        ssum += __shfl_xor(ssum, 1);
        ssum += __shfl_xor(ssum, 2);
        ssum += __shfl_xor(ssum, 4);
        ssum += __shfl_xor(ssum, 8);
        l_run[m][j] = l_run[m][j] * alpha + ssum;
#pragma unroll
        for (int nf = 0; nf < 8; ++nf) acc_o[m][nf][j] *= alpha;
      }
#pragma unroll
    for (int m = 0; m < 2; ++m)
#pragma unroll
      for (int j = 0; j < 4; ++j) {
        int prow = m * 16 + lg * 4 + j;
        int swz  = (prow & 7) << 4;
#pragma unroll
        for (int nf = 0; nf < 4; ++nf) {
          int wbyte = ((nf * 16 + l16) * 2) ^ swz;
          *(bf16_t*)((char*)Ps[w] + prow * 128 + wbyte) = (__bf16)sc[m][nf][j];
        }
      }
#pragma unroll
    for (int kk2 = 0; kk2 < 2; ++kk2) {
      bf16x8 pf[2];
#pragma unroll
      for (int m = 0; m < 2; ++m) {
        int prow = m * 16 + l16;
        int cb = (kk2 * 64 + lg * 16) ^ ((prow & 7) << 4);
        pf[m] = *reinterpret_cast<const bf16x8*>(
            (const char*)Ps[w] + prow * 128 + cb);
      }
#pragma unroll
      for (int nf = 0; nf < 8; ++nf) {
        int d = nf * 16 + l16;
        int cb = (kk2 * 64 + lg * 16) ^ ((d & 7) << 4);
        bf16x8 vf = *reinterpret_cast<const bf16x8*>(
            (const char*)Vs[cur] + d * 128 + cb);
#pragma unroll
        for (int m = 0; m < 2; ++m)
          acc_o[m][nf] = __builtin_amdgcn_mfma_f32_16x16x32_bf16(
              pf[m], vf, acc_o[m][nf], 0, 0, 0);
      }
    }
  }

#pragma unroll
  for (int m = 0; m < 2; ++m) {
    const int tglob = qbase + w * 32 + m * 16 + lg * 4;
#pragma unroll
    for (int j = 0; j < 4; ++j) {
      float inv_l = 1.0f / l_run[m][j];
#pragma unroll
      for (int nf = 0; nf < 8; ++nf)
        Ctx[((size_t)(b * kT + tglob + j) * kH + h) * kDH + nf * 16 + l16] =
            (__bf16)(acc_o[m][nf][j] * inv_l);
    }
  }
}

// ---------------------------------------------------------------------------
extern "C" void kernel_launch(void* const* d_in, const int* in_sizes, int n_in,
                              void* d_out, int out_size, void* d_ws, size_t ws_size,
                              hipStream_t stream) {
  (void)in_sizes; (void)n_in; (void)out_size; (void)ws_size;
  const float* x  = (const float*)d_in[0];
  const float* Wq = (const float*)d_in[1];
  const float* Wk = (const float*)d_in[2];
  const float* Wv = (const float*)d_in[3];
  const float* Wo = (const float*)d_in[4];
  float* out = (float*)d_out;

  // allow 128KB dynamic LDS for the GEMMs (idempotent host-side config)
  hipFuncSetAttribute((const void*)gemm_nt_k<true>,
                      hipFuncAttributeMaxDynamicSharedMemorySize, 131072);
  hipFuncSetAttribute((const void*)gemm_nt_k<false>,
                      hipFuncAttributeMaxDynamicSharedMemorySize, 131072);

  char* ws = (char*)d_ws;
  size_t off = 0;
  auto alloc = [&](size_t bytes) -> char* {
    char* p = ws + off;
    off += (bytes + 255) & ~(size_t)255;
    return p;
  };
  bf16_t* xb    = (bf16_t*)alloc((size_t)kM * kE * 2);          // 33.5 MB
  bf16_t* Wqkvb = (bf16_t*)alloc((size_t)kNQKV * kE * 2);       // 50.3 MB
  bf16_t* Wob   = (bf16_t*)alloc((size_t)kE * kE * 2);          // 33.5 MB
  bf16_t* QKV   = (bf16_t*)alloc((size_t)kM * kNQKV * 2);       // 50.3 MB
  float*  cosT  = (float*)alloc((size_t)kT * 64 * 4);
  float*  sinT  = (float*)alloc((size_t)kT * 64 * 4);
  // aliases (dead-after-QKV-GEMM regions):
  bf16_t* Qr  = Wqkvb;                                          // [B,H,T,DH]
  bf16_t* Kr  = Wqkvb + (size_t)kE * kE;                        // [B,HKV,T,DH]
  bf16_t* Vt  = Wqkvb + (size_t)(kE + kHKV * kDH) * kE;         // [B,HKV,DH,T]
  bf16_t* Ctx = xb;                                             // [B,T,H,DH]

  // casts
  cast_f32_bf16_k<<<16384, 256, 0, stream>>>(x, xb, kM * kE / 4);
  cast_f32_bf16_k<<<16384, 256, 0, stream>>>(Wq, Wqkvb, kE * kE / 4);
  cast_f32_bf16_k<<<4096, 256, 0, stream>>>(Wk, Wqkvb + (size_t)kE * kE,
                                            kHKV * kDH * kE / 4);
  cast_f32_bf16_k<<<4096, 256, 0, stream>>>(Wv, Wqkvb + (size_t)(kE + kHKV * kDH) * kE,
                                            kHKV * kDH * kE / 4);
  cast_f32_bf16_k<<<16384, 256, 0, stream>>>(Wo, Wob, kE * kE / 4);
  rope_table_k<<<512, 256, 0, stream>>>(cosT, sinT);

  // fused QKV projection: [4096,6144] = xb @ Wqkvb^T  (384 blocks, 8 | 384)
  gemm_nt_k<true><<<(kM / 256) * (kNQKV / 256), 512, 131072, stream>>>(
      xb, Wqkvb, QKV, kM, kNQKV, kE);
  // rope + layout
  rope_q_k<<<32768, 256, 0, stream>>>(QKV, cosT, sinT, Qr);
  rope_k_k<<<8192, 256, 0, stream>>>(QKV, cosT, sinT, Kr);
  vtrans_k<<<512, 256, 0, stream>>>(QKV, Vt);
  // attention: B*H*(T/128) = 1024 blocks
  flash_k<<<kB * kH * (kT / 128), 256, 0, stream>>>(Qr, Kr, Vt, Ctx);
  // output projection (fp32 out): 256 blocks
  gemm_nt_k<false><<<(kM / 256) * (kE / 256), 512, 131072, stream>>>(
      Ctx, Wob, out, kM, kE, kE);
}